// Round 6
// baseline (321.075 us; speedup 1.0000x reference)
//
#include <hip/hip_runtime.h>

typedef _Float16 half8 __attribute__((ext_vector_type(8)));
typedef _Float16 half4v __attribute__((ext_vector_type(4)));
typedef _Float16 half2v __attribute__((ext_vector_type(2)));
typedef float floatx4 __attribute__((ext_vector_type(4)));

#define AS3 __attribute__((address_space(3)))
#define AS1 __attribute__((address_space(1)))

// ---------------- fused f32 -> f16 convert of all three inputs ----------------
__global__ __launch_bounds__(256) void cvt_all(const float* __restrict__ x,
                                               const float* __restrict__ wq,
                                               const float* __restrict__ wp,
                                               _Float16* __restrict__ xh,
                                               _Float16* __restrict__ wqh,
                                               _Float16* __restrict__ wph) {
    long i = (long)blockIdx.x * 256 + threadIdx.x;   // float4 index
    const float4* src; half4v* dst; long off;
    if (i < 2097152)      { src = (const float4*)x;  dst = (half4v*)xh;  off = i; }
    else if (i < 2883584) { src = (const float4*)wq; dst = (half4v*)wqh; off = i - 2097152; }
    else                  { src = (const float4*)wp; dst = (half4v*)wph; off = i - 2883584; }
    float4 v = src[off];
    half4v h = {(_Float16)v.x, (_Float16)v.y, (_Float16)v.z, (_Float16)v.w};
    dst[off] = h;
}

// ---------------- TN GEMM: A via LDS-dbuf pipeline, B direct from global ------
// C[M,N] = A[M,K] * B[N,K]^T. 128x128 tile, BK=32, 256 threads.
// B-fragments (weights, L2-hot) are loaded straight from global with register
// prefetch distance 1 -- they never touch LDS. Only A is staged, via the R5
// global->VGPR->LDS double-buffer (fine-grained vmcnt at the ds_write, free
// barrier drain). LDS traffic/iter: 48KB -> 24KB (write 8 + read 16).
__global__ __launch_bounds__(256, 3) void gemm_tn(
    const _Float16* __restrict__ A, const _Float16* __restrict__ B,
    _Float16* __restrict__ Ch, int ldc, _Float16* __restrict__ Ch2, int ldc2, int split,
    float* __restrict__ Cf, const float* __restrict__ bias,
    int M, int Nn, int K)
{
    __shared__ _Float16 sA[2][128 * 32];
    const int tid  = threadIdx.x;
    const int lane = tid & 63, wave = tid >> 6;
    const int quad = lane >> 4, l16 = lane & 15;
    const int wr = wave >> 1, wc = wave & 1;
    const long m0 = (long)blockIdx.x * 128, n0 = (long)blockIdx.y * 128;

    // A staging: thread owns 16B chunk (tid&3) of rows srow, srow+64. LDS slot
    // swizzle: chunk c of row r -> slot c ^ ((r>>1)&3)  (bank-uniform reads,
    // verified R3: SQ_LDS_BANK_CONFLICT = 0).
    const int srow = tid >> 2;
    const int sslot = ((tid & 3) ^ ((srow >> 1) & 3)) * 8;
    const int dlo = srow * 32 + sslot;
    const int dhi = (srow + 64) * 32 + sslot;
    const _Float16* gA0 = A + (m0 + srow) * (long)K + (tid & 3) * 8;
    const _Float16* gA1 = A + (m0 + srow + 64) * (long)K + (tid & 3) * 8;

    // B fragment base pointers: B[n0 + wc*64 + tn*16 + l16][quad*8 + k0]
    const _Float16* gB0 = B + (n0 + wc * 64 + l16) * (long)K + quad * 8;
    const _Float16* gBf[4] = {gB0, gB0 + 16 * (long)K, gB0 + 32 * (long)K, gB0 + 48 * (long)K};

    const int swz = (l16 >> 1) & 3;
    const int aoff = ((quad ^ swz) * 8);

    floatx4 acc[4][4] = {};
    const int nk = K >> 5;

    // prologue: A tile 0 -> VGPR -> LDS buf 0; B frags for iter 0 -> regs
    half8 rA0 = *(const half8*)gA0, rA1 = *(const half8*)gA1;
    half8 bf[4], bn[4];
#pragma unroll
    for (int tn = 0; tn < 4; tn++) bf[tn] = *(const half8*)gBf[tn];
    *(half8*)&sA[0][dlo] = rA0; *(half8*)&sA[0][dhi] = rA1;

    for (int kk = 0; kk < nk; kk++) {
        const int cur = kk & 1;
        __syncthreads();                 // vmcnt already drained; lgkm only
        const bool more = (kk + 1 < nk);
        if (more) {
            const long k0n = (long)(kk + 1) << 5;
            rA0 = *(const half8*)(gA0 + k0n);
            rA1 = *(const half8*)(gA1 + k0n);
#pragma unroll
            for (int tn = 0; tn < 4; tn++) bn[tn] = *(const half8*)(gBf[tn] + k0n);
        }

        const _Float16* cA = &sA[cur][0];
        half8 af[4];
#pragma unroll
        for (int t = 0; t < 4; t++)
            af[t] = *(const half8*)&cA[(wr * 64 + t * 16 + l16) * 32 + aoff];
#pragma unroll
        for (int tm = 0; tm < 4; tm++)
#pragma unroll
            for (int tn = 0; tn < 4; tn++)
                acc[tm][tn] = __builtin_amdgcn_mfma_f32_16x16x32_f16(af[tm], bf[tn], acc[tm][tn], 0, 0, 0);

        if (more) {
            _Float16* nA = &sA[cur ^ 1][0];
            *(half8*)&nA[dlo] = rA0;     // vmcnt wait lands here, one phase after issue
            *(half8*)&nA[dhi] = rA1;
#pragma unroll
            for (int tn = 0; tn < 4; tn++) bf[tn] = bn[tn];
        }
    }

    // epilogue: C/D layout col=lane&15, row=quad*4+reg (verified m89/m91)
    const bool useC2 = (Cf == nullptr) && (n0 >= split);
#pragma unroll
    for (int tm = 0; tm < 4; tm++) {
        long row = m0 + wr * 64 + tm * 16 + quad * 4;
#pragma unroll
        for (int tn = 0; tn < 4; tn++) {
            long col = n0 + wc * 64 + tn * 16 + l16;
            float bv = bias ? bias[col] : 0.f;
#pragma unroll
            for (int r = 0; r < 4; r++) {
                float v = acc[tm][tn][r];
                if (Cf)        Cf[(row + r) * (long)Nn + col] = v + bv;
                else if (useC2) Ch2[(row + r) * (long)ldc2 + (col - split)] = (_Float16)v;
                else           Ch[(row + r) * (long)ldc + col] = (_Float16)v;
            }
        }
    }
}

// ---------------- V transpose: vh [B*N][1024] -> vt [B*H][64][1024] ----------------
__global__ __launch_bounds__(256) void transpose_v(const _Float16* __restrict__ vh,
                                                   _Float16* __restrict__ vt) {
    const int bh = blockIdx.x;          // b*16+h
    const int b = bh >> 4, h = bh & 15;
    const int n0 = blockIdx.y * 64;
    const int d = threadIdx.x & 63;
    const int ng = threadIdx.x >> 6;
#pragma unroll
    for (int i = 0; i < 2; i++) {
        int nb = (ng + 4 * i) * 8;
        half8 vv;
#pragma unroll
        for (int j = 0; j < 8; j++)
            vv[j] = vh[(long)(b * 1024 + n0 + nb + j) * 1024 + h * 64 + d];
        *(half8*)&vt[((long)(bh * 64 + d)) * 1024 + n0 + nb] = vv;
    }
}

// ---------------- flash attention (S^T orientation) ----------------
#define CSC 0.125f
__global__ __launch_bounds__(256, 4) void flash_attn(const _Float16* __restrict__ qk,
                                                     const _Float16* __restrict__ vt,
                                                     _Float16* __restrict__ out)
{
    const int bh = blockIdx.x, b = bh >> 4, h = bh & 15;
    const int n0 = blockIdx.y * 128;
    const int tid = threadIdx.x, lane = tid & 63, wave = tid >> 6;
    const int quad = lane >> 4, l16 = lane & 15;

    __shared__ _Float16 sK[64 * 72];        // [kr][d] pad 72
    __shared__ _Float16 sVT[64 * 72];       // [d][kr] pad 72
    __shared__ _Float16 sPT[4][32 * 72];    // per-wave P^T round-trip [q][kr], reused as sOut

    half8 qf[2][2];
    const _Float16* qbase = qk + (long)(b * 1024 + n0 + wave * 32) * 2048 + h * 64;
#pragma unroll
    for (int t = 0; t < 2; t++)
#pragma unroll
        for (int s = 0; s < 2; s++)
            qf[t][s] = *(const half8*)(qbase + (long)(t * 16 + l16) * 2048 + s * 32 + quad * 8);

    const int srow = tid >> 3, scol8 = (tid & 7) * 8;
    const _Float16* kgb = qk + 1024 + h * 64 + scol8 + (long)(b * 1024 + srow) * 2048;
    const _Float16* vgb = vt + (long)(bh * 64 + srow) * 1024 + scol8;

    float m_[2] = {-1e30f, -1e30f}, l_[2] = {0.f, 0.f};
    floatx4 o[2][4] = {};

    for (int kt = 0; kt < 16; kt++) {
        const int kr0 = kt * 64;
        __syncthreads();
#pragma unroll
        for (int i = 0; i < 2; i++) {
            int r = srow + i * 32;
            *(half8*)&sK[r * 72 + scol8]  = *(const half8*)(kgb + (long)(kr0 + i * 32) * 2048);
            *(half8*)&sVT[r * 72 + scol8] = *(const half8*)(vgb + (long)(i * 32) * 1024 + kr0);
        }
        __syncthreads();

        // S^T = K Q^T: A=K (m=kr), B=Q (n=q). C-layout: kr=c*16+quad*4+r, q=t*16+l16
        floatx4 sacc[2][4] = {};
#pragma unroll
        for (int c = 0; c < 4; c++)
#pragma unroll
            for (int s = 0; s < 2; s++) {
                half8 kf = *(const half8*)&sK[(c * 16 + l16) * 72 + s * 32 + quad * 8];
                sacc[0][c] = __builtin_amdgcn_mfma_f32_16x16x32_f16(kf, qf[0][s], sacc[0][c], 0, 0, 0);
                sacc[1][c] = __builtin_amdgcn_mfma_f32_16x16x32_f16(kf, qf[1][s], sacc[1][c], 0, 0, 0);
            }

        // online softmax over kr: in-lane reduce + 2 shuffles (xor16, xor32)
#pragma unroll
        for (int t = 0; t < 2; t++) {
            float mx = -1e30f;
#pragma unroll
            for (int c = 0; c < 4; c++)
#pragma unroll
                for (int r = 0; r < 4; r++) {
                    float v = sacc[t][c][r] * CSC;
                    sacc[t][c][r] = v;
                    mx = fmaxf(mx, v);
                }
            mx = fmaxf(mx, __shfl_xor(mx, 16));
            mx = fmaxf(mx, __shfl_xor(mx, 32));
            float mn = fmaxf(m_[t], mx);
            float al = __expf(m_[t] - mn);
            m_[t] = mn;
            float rs = 0.f;
#pragma unroll
            for (int c = 0; c < 4; c++)
#pragma unroll
                for (int r = 0; r < 4; r++) {
                    float p = __expf(sacc[t][c][r] - mn);
                    sacc[t][c][r] = p;
                    rs += p;
                }
            rs += __shfl_xor(rs, 16);
            rs += __shfl_xor(rs, 32);
            l_[t] = l_[t] * al + rs;
#pragma unroll
            for (int dt = 0; dt < 4; dt++) o[t][dt] *= al;
#pragma unroll
            for (int c = 0; c < 4; c++) {
                half2v p01 = {(_Float16)sacc[t][c][0], (_Float16)sacc[t][c][1]};
                half2v p23 = {(_Float16)sacc[t][c][2], (_Float16)sacc[t][c][3]};
                *(half2v*)&sPT[wave][(t * 16 + l16) * 72 + c * 16 + quad * 4]     = p01;
                *(half2v*)&sPT[wave][(t * 16 + l16) * 72 + c * 16 + quad * 4 + 2] = p23;
            }
        }

        // PV: O^T += V^T P^T. A = V^T (m=d), B = P (n=q) from sPT.
#pragma unroll
        for (int kk = 0; kk < 2; kk++) {
            half8 pf0 = *(const half8*)&sPT[wave][(l16) * 72 + kk * 32 + quad * 8];
            half8 pf1 = *(const half8*)&sPT[wave][(16 + l16) * 72 + kk * 32 + quad * 8];
#pragma unroll
            for (int dt = 0; dt < 4; dt++) {
                half8 vf = *(const half8*)&sVT[(dt * 16 + l16) * 72 + kk * 32 + quad * 8];
                o[0][dt] = __builtin_amdgcn_mfma_f32_16x16x32_f16(vf, pf0, o[0][dt], 0, 0, 0);
                o[1][dt] = __builtin_amdgcn_mfma_f32_16x16x32_f16(vf, pf1, o[1][dt], 0, 0, 0);
            }
        }
    }

    // epilogue: normalize, per-wave LDS transpose (O^T -> O), coalesced 16B stores
#pragma unroll
    for (int t = 0; t < 2; t++) {
        float inv = 1.f / l_[t];
#pragma unroll
        for (int dt = 0; dt < 4; dt++) {
            floatx4 v = o[t][dt];
            half2v a = {(_Float16)(v[0] * inv), (_Float16)(v[1] * inv)};
            half2v c = {(_Float16)(v[2] * inv), (_Float16)(v[3] * inv)};
            *(half2v*)&sPT[wave][(t * 16 + l16) * 72 + dt * 16 + quad * 4]     = a;
            *(half2v*)&sPT[wave][(t * 16 + l16) * 72 + dt * 16 + quad * 4 + 2] = c;
        }
    }
    __syncthreads();
#pragma unroll
    for (int i = 0; i < 4; i++) {
        int ql = i * 8 + (lane >> 3);
        int c8 = (lane & 7) * 8;
        half8 vv = *(const half8*)&sPT[wave][ql * 72 + c8];
        *(half8*)(out + (long)(b * 1024 + n0 + wave * 32 + ql) * 1024 + h * 64 + c8) = vv;
    }
}

// ---------------- launch ----------------
extern "C" void kernel_launch(void* const* d_in, const int* in_sizes, int n_in,
                              void* d_out, int out_size, void* d_ws, size_t ws_size,
                              hipStream_t stream) {
    const float* x      = (const float*)d_in[0];
    const float* w_qkv  = (const float*)d_in[1];
    const float* w_proj = (const float*)d_in[2];
    const float* b_proj = (const float*)d_in[3];

    char* ws = (char*)d_ws;
    _Float16* qkh    = (_Float16*)ws;                      // 32MB [8192][2048] (Q|K)
    _Float16* vh     = (_Float16*)(ws + 33554432);         // 16MB [8192][1024] (V); attnh alias
    _Float16* xh     = (_Float16*)(ws + 50331648);         // 16MB [8192][1024]; vT alias
    _Float16* wqkvh  = (_Float16*)(ws + 67108864);         // 6MB [3072][1024]
    _Float16* wprojh = (_Float16*)(ws + 73400320);         // 2MB [1024][1024]
    _Float16* vT     = xh;                                 // [128][64][1024] after GEMM1
    _Float16* attnh  = vh;                                 // flash out, after transpose

    cvt_all<<<12288, 256, 0, stream>>>(x, w_qkv, w_proj, xh, wqkvh, wprojh);

    // QKV GEMM: cols 0..2047 -> qkh, cols 2048..3071 -> vh
    gemm_tn<<<dim3(64, 24), 256, 0, stream>>>(xh, wqkvh, qkh, 2048, vh, 1024, 2048,
                                              nullptr, nullptr, 8192, 3072, 1024);
    transpose_v<<<dim3(128, 16), 256, 0, stream>>>(vh, vT);
    flash_attn<<<dim3(128, 8), 256, 0, stream>>>(qkh, vT, attnh);
    gemm_tn<<<dim3(64, 8), 256, 0, stream>>>(attnh, wprojh, nullptr, 0, nullptr, 0, 1 << 30,
                                             (float*)d_out, b_proj, 8192, 1024, 1024);
}

// Round 7
// 248.276 us; speedup vs baseline: 1.2932x; 1.2932x over previous
//
#include <hip/hip_runtime.h>

typedef _Float16 half8 __attribute__((ext_vector_type(8)));
typedef _Float16 half4v __attribute__((ext_vector_type(4)));
typedef _Float16 half2v __attribute__((ext_vector_type(2)));
typedef float floatx4 __attribute__((ext_vector_type(4)));

#define AS3 __attribute__((address_space(3)))
#define AS1 __attribute__((address_space(1)))

// ---------------- fused f32 -> f16 convert of all three inputs ----------------
__global__ __launch_bounds__(256) void cvt_all(const float* __restrict__ x,
                                               const float* __restrict__ wq,
                                               const float* __restrict__ wp,
                                               _Float16* __restrict__ xh,
                                               _Float16* __restrict__ wqh,
                                               _Float16* __restrict__ wph) {
    long i = (long)blockIdx.x * 256 + threadIdx.x;   // float4 index
    const float4* src; half4v* dst; long off;
    if (i < 2097152)      { src = (const float4*)x;  dst = (half4v*)xh;  off = i; }
    else if (i < 2883584) { src = (const float4*)wq; dst = (half4v*)wqh; off = i - 2097152; }
    else                  { src = (const float4*)wp; dst = (half4v*)wph; off = i - 2883584; }
    float4 v = src[off];
    half4v h = {(_Float16)v.x, (_Float16)v.y, (_Float16)v.z, (_Float16)v.w};
    dst[off] = h;
}

// ---------------- TN GEMM, global->VGPR->LDS pipeline, XOR-swizzled ----------
// C[M,N] = A[M,K] * B[N,K]^T. 128x128 tile, BK=32, 256 threads, dbuf LDS.
// (R5 structure, 81us: staging loads -> VGPR right after barrier, compute from
// LDS, ds_write regs -> other buffer; fine-grained vmcnt at the ds_write, free
// barrier drain. R6's B-direct-from-global regressed: 16 scattered 64B
// segments per B-frag load = 4x TA transactions.)
// Columns >= split are written TRANSPOSED into Vt[bh*64+d][n] (8B half4
// stores; m-rows are consecutive n there). Vt path assumes M,N layout of the
// QKV problem (row>>10 = b, (col-split)>>6 = h).
__global__ __launch_bounds__(256, 4) void gemm_tn(
    const _Float16* __restrict__ A, const _Float16* __restrict__ B,
    _Float16* __restrict__ Ch, int ldc, _Float16* __restrict__ Vt, int split,
    float* __restrict__ Cf, const float* __restrict__ bias,
    int M, int Nn, int K)
{
    __shared__ _Float16 sA[2][128 * 32];
    __shared__ _Float16 sB[2][128 * 32];
    const int tid  = threadIdx.x;
    const int lane = tid & 63, wave = tid >> 6;
    const int quad = lane >> 4, l16 = lane & 15;
    const int wr = wave >> 1, wc = wave & 1;
    const long m0 = (long)blockIdx.x * 128, n0 = (long)blockIdx.y * 128;

    // thread tid owns row srow (and srow+64), 16B chunk (tid&3) of the 64B k-row.
    // LDS placement: chunk c of row r -> slot c ^ ((r>>1)&3) (involution;
    // bank-uniform fragment reads, verified R3: SQ_LDS_BANK_CONFLICT = 0).
    const int srow = tid >> 2;
    const int sslot = ((tid & 3) ^ ((srow >> 1) & 3)) * 8;
    const int dlo = srow * 32 + sslot;
    const int dhi = (srow + 64) * 32 + sslot;
    const _Float16* gA0 = A + (m0 + srow) * (long)K + (tid & 3) * 8;
    const _Float16* gA1 = A + (m0 + srow + 64) * (long)K + (tid & 3) * 8;
    const _Float16* gB0 = B + (n0 + srow) * (long)K + (tid & 3) * 8;
    const _Float16* gB1 = B + (n0 + srow + 64) * (long)K + (tid & 3) * 8;

    const int swz = (l16 >> 1) & 3;
    const int aoff = ((quad ^ swz) * 8);

    floatx4 acc[4][4] = {};
    const int nk = K >> 5;

    // prologue: tile 0 -> VGPR -> LDS buf 0
    half8 rA0 = *(const half8*)gA0, rA1 = *(const half8*)gA1;
    half8 rB0 = *(const half8*)gB0, rB1 = *(const half8*)gB1;
    *(half8*)&sA[0][dlo] = rA0; *(half8*)&sA[0][dhi] = rA1;
    *(half8*)&sB[0][dlo] = rB0; *(half8*)&sB[0][dhi] = rB1;

    for (int kk = 0; kk < nk; kk++) {
        const int cur = kk & 1;
        __syncthreads();               // lgkm drain only; vmcnt already 0 here
        const bool more = (kk + 1 < nk);
        if (more) {
            const long k0 = (long)(kk + 1) << 5;
            rA0 = *(const half8*)(gA0 + k0); rA1 = *(const half8*)(gA1 + k0);
            rB0 = *(const half8*)(gB0 + k0); rB1 = *(const half8*)(gB1 + k0);
        }

        const _Float16* cA = &sA[cur][0];
        const _Float16* cB = &sB[cur][0];
        half8 af[4], bf[4];
#pragma unroll
        for (int t = 0; t < 4; t++)
            af[t] = *(const half8*)&cA[(wr * 64 + t * 16 + l16) * 32 + aoff];
#pragma unroll
        for (int t = 0; t < 4; t++)
            bf[t] = *(const half8*)&cB[(wc * 64 + t * 16 + l16) * 32 + aoff];
#pragma unroll
        for (int tm = 0; tm < 4; tm++)
#pragma unroll
            for (int tn = 0; tn < 4; tn++)
                acc[tm][tn] = __builtin_amdgcn_mfma_f32_16x16x32_f16(af[tm], bf[tn], acc[tm][tn], 0, 0, 0);

        if (more) {
            _Float16* nA = &sA[cur ^ 1][0];
            _Float16* nB = &sB[cur ^ 1][0];
            *(half8*)&nA[dlo] = rA0; *(half8*)&nA[dhi] = rA1;   // vmcnt wait lands here,
            *(half8*)&nB[dlo] = rB0; *(half8*)&nB[dhi] = rB1;   // one compute phase after issue
        }
    }

    // epilogue: C/D layout col=lane&15, row=quad*4+reg (verified m89/m91)
#pragma unroll
    for (int tm = 0; tm < 4; tm++) {
        long row = m0 + wr * 64 + tm * 16 + quad * 4;
#pragma unroll
        for (int tn = 0; tn < 4; tn++) {
            long col = n0 + wc * 64 + tn * 16 + l16;
            if (Cf) {
                float bv = bias ? bias[col] : 0.f;
#pragma unroll
                for (int r = 0; r < 4; r++)
                    Cf[(row + r) * (long)Nn + col] = acc[tm][tn][r] + bv;
            } else if (col >= split) {
                // transposed V write: Vt[(b*16+h)*64+d][n], n = 4 consecutive rows
                long cv = col - split;
                long vrow = ((row >> 10) * 16 + (cv >> 6)) * 64 + (cv & 63);
                long nn = row & 1023;
                half4v pv = {(_Float16)acc[tm][tn][0], (_Float16)acc[tm][tn][1],
                             (_Float16)acc[tm][tn][2], (_Float16)acc[tm][tn][3]};
                *(half4v*)&Vt[vrow * 1024 + nn] = pv;
            } else {
#pragma unroll
                for (int r = 0; r < 4; r++)
                    Ch[(row + r) * (long)ldc + col] = (_Float16)acc[tm][tn][r];
            }
        }
    }
}

// ---------------- flash attention (S^T orientation) ----------------
#define CSC 0.125f
__global__ __launch_bounds__(256, 4) void flash_attn(const _Float16* __restrict__ qk,
                                                     const _Float16* __restrict__ vt,
                                                     _Float16* __restrict__ out)
{
    const int bh = blockIdx.x, b = bh >> 4, h = bh & 15;
    const int n0 = blockIdx.y * 128;
    const int tid = threadIdx.x, lane = tid & 63, wave = tid >> 6;
    const int quad = lane >> 4, l16 = lane & 15;

    __shared__ _Float16 sK[64 * 72];        // [kr][d] pad 72
    __shared__ _Float16 sVT[64 * 72];       // [d][kr] pad 72
    __shared__ _Float16 sPT[4][32 * 72];    // per-wave P^T round-trip [q][kr], reused as sOut

    half8 qf[2][2];
    const _Float16* qbase = qk + (long)(b * 1024 + n0 + wave * 32) * 2048 + h * 64;
#pragma unroll
    for (int t = 0; t < 2; t++)
#pragma unroll
        for (int s = 0; s < 2; s++)
            qf[t][s] = *(const half8*)(qbase + (long)(t * 16 + l16) * 2048 + s * 32 + quad * 8);

    const int srow = tid >> 3, scol8 = (tid & 7) * 8;
    const _Float16* kgb = qk + 1024 + h * 64 + scol8 + (long)(b * 1024 + srow) * 2048;
    const _Float16* vgb = vt + (long)(bh * 64 + srow) * 1024 + scol8;

    float m_[2] = {-1e30f, -1e30f}, l_[2] = {0.f, 0.f};
    floatx4 o[2][4] = {};

    for (int kt = 0; kt < 16; kt++) {
        const int kr0 = kt * 64;
        __syncthreads();
#pragma unroll
        for (int i = 0; i < 2; i++) {
            int r = srow + i * 32;
            *(half8*)&sK[r * 72 + scol8]  = *(const half8*)(kgb + (long)(kr0 + i * 32) * 2048);
            *(half8*)&sVT[r * 72 + scol8] = *(const half8*)(vgb + (long)(i * 32) * 1024 + kr0);
        }
        __syncthreads();

        // S^T = K Q^T: A=K (m=kr), B=Q (n=q). C-layout: kr=c*16+quad*4+r, q=t*16+l16
        floatx4 sacc[2][4] = {};
#pragma unroll
        for (int c = 0; c < 4; c++)
#pragma unroll
            for (int s = 0; s < 2; s++) {
                half8 kf = *(const half8*)&sK[(c * 16 + l16) * 72 + s * 32 + quad * 8];
                sacc[0][c] = __builtin_amdgcn_mfma_f32_16x16x32_f16(kf, qf[0][s], sacc[0][c], 0, 0, 0);
                sacc[1][c] = __builtin_amdgcn_mfma_f32_16x16x32_f16(kf, qf[1][s], sacc[1][c], 0, 0, 0);
            }

        // online softmax over kr: in-lane reduce + 2 shuffles (xor16, xor32)
#pragma unroll
        for (int t = 0; t < 2; t++) {
            float mx = -1e30f;
#pragma unroll
            for (int c = 0; c < 4; c++)
#pragma unroll
                for (int r = 0; r < 4; r++) {
                    float v = sacc[t][c][r] * CSC;
                    sacc[t][c][r] = v;
                    mx = fmaxf(mx, v);
                }
            mx = fmaxf(mx, __shfl_xor(mx, 16));
            mx = fmaxf(mx, __shfl_xor(mx, 32));
            float mn = fmaxf(m_[t], mx);
            float al = __expf(m_[t] - mn);
            m_[t] = mn;
            float rs = 0.f;
#pragma unroll
            for (int c = 0; c < 4; c++)
#pragma unroll
                for (int r = 0; r < 4; r++) {
                    float p = __expf(sacc[t][c][r] - mn);
                    sacc[t][c][r] = p;
                    rs += p;
                }
            rs += __shfl_xor(rs, 16);
            rs += __shfl_xor(rs, 32);
            l_[t] = l_[t] * al + rs;
#pragma unroll
            for (int dt = 0; dt < 4; dt++) o[t][dt] *= al;
            // pack P^T -> sPT[q][kr], one 8B half4 write per c-tile
#pragma unroll
            for (int c = 0; c < 4; c++) {
                half4v p = {(_Float16)sacc[t][c][0], (_Float16)sacc[t][c][1],
                            (_Float16)sacc[t][c][2], (_Float16)sacc[t][c][3]};
                *(half4v*)&sPT[wave][(t * 16 + l16) * 72 + c * 16 + quad * 4] = p;
            }
        }

        // PV: O^T += V^T P^T. A = V^T (m=d), B = P (n=q) from sPT.
#pragma unroll
        for (int kk = 0; kk < 2; kk++) {
            half8 pf0 = *(const half8*)&sPT[wave][(l16) * 72 + kk * 32 + quad * 8];
            half8 pf1 = *(const half8*)&sPT[wave][(16 + l16) * 72 + kk * 32 + quad * 8];
#pragma unroll
            for (int dt = 0; dt < 4; dt++) {
                half8 vf = *(const half8*)&sVT[(dt * 16 + l16) * 72 + kk * 32 + quad * 8];
                o[0][dt] = __builtin_amdgcn_mfma_f32_16x16x32_f16(vf, pf0, o[0][dt], 0, 0, 0);
                o[1][dt] = __builtin_amdgcn_mfma_f32_16x16x32_f16(vf, pf1, o[1][dt], 0, 0, 0);
            }
        }
    }

    // epilogue: normalize, per-wave LDS transpose (O^T -> O), coalesced 16B stores
#pragma unroll
    for (int t = 0; t < 2; t++) {
        float inv = 1.f / l_[t];
#pragma unroll
        for (int dt = 0; dt < 4; dt++) {
            floatx4 v = o[t][dt];
            half4v a = {(_Float16)(v[0] * inv), (_Float16)(v[1] * inv),
                        (_Float16)(v[2] * inv), (_Float16)(v[3] * inv)};
            *(half4v*)&sPT[wave][(t * 16 + l16) * 72 + dt * 16 + quad * 4] = a;
        }
    }
    __syncthreads();
#pragma unroll
    for (int i = 0; i < 4; i++) {
        int ql = i * 8 + (lane >> 3);
        int c8 = (lane & 7) * 8;
        half8 vv = *(const half8*)&sPT[wave][ql * 72 + c8];
        *(half8*)(out + (long)(b * 1024 + n0 + wave * 32 + ql) * 1024 + h * 64 + c8) = vv;
    }
}

// ---------------- launch ----------------
extern "C" void kernel_launch(void* const* d_in, const int* in_sizes, int n_in,
                              void* d_out, int out_size, void* d_ws, size_t ws_size,
                              hipStream_t stream) {
    const float* x      = (const float*)d_in[0];
    const float* w_qkv  = (const float*)d_in[1];
    const float* w_proj = (const float*)d_in[2];
    const float* b_proj = (const float*)d_in[3];

    char* ws = (char*)d_ws;
    _Float16* qkh    = (_Float16*)ws;                      // 32MB [8192][2048] (Q|K)
    _Float16* vT     = (_Float16*)(ws + 33554432);         // 16MB [128*64][1024] (V^T), by GEMM1
    _Float16* xh     = (_Float16*)(ws + 50331648);         // 16MB [8192][1024]; attnh alias
    _Float16* wqkvh  = (_Float16*)(ws + 67108864);         // 6MB [3072][1024]
    _Float16* wprojh = (_Float16*)(ws + 73400320);         // 2MB [1024][1024]
    _Float16* attnh  = xh;                                 // flash out (xh dead after GEMM1)

    cvt_all<<<12288, 256, 0, stream>>>(x, w_qkv, w_proj, xh, wqkvh, wprojh);

    // QKV GEMM: cols 0..2047 -> qkh row-major, cols 2048..3071 -> vT transposed
    gemm_tn<<<dim3(64, 24), 256, 0, stream>>>(xh, wqkvh, qkh, 2048, vT, 2048,
                                              nullptr, nullptr, 8192, 3072, 1024);
    flash_attn<<<dim3(128, 8), 256, 0, stream>>>(qkh, vT, attnh);
    gemm_tn<<<dim3(64, 8), 256, 0, stream>>>(attnh, wprojh, nullptr, 0, nullptr, 1 << 30,
                                             (float*)d_out, b_proj, 8192, 1024, 1024);
}